// Round 12
// baseline (361.763 us; speedup 1.0000x reference)
//
#include <hip/hip_runtime.h>
#include <hip/hip_bf16.h>

#define BSZ 4
#define NN  256
#define DXX 256
#define DEE 64
#define DYY 64

// ---- workspace layout (float offsets) ----
// R12: EPART is a tiny global accumulator: esum[4][64] | esq[4][64] | emax_enc[4][64]
// | emin_enc[4][64] = 1024 floats. ws high-water = 1058816 floats (4.24 MB) — back
// UNDER the old proven 4.49 MB footprint (R11's 5.28 MB overflowed ws and corrupted
// adjacent input buffers -> post-replay divergence).
#define OFF_Q     0          // 262144  (row-major [b][i][c])
#define OFF_K     262144     // 262144  (TRANSPOSED: [b][c][j])
#define OFF_V     524288     // 262144  (TRANSPOSED: [b][c][j])
#define OFF_XW    786432     // 262144
#define OFF_YE1   1048576    // 1024
#define OFF_YE2   1049600    // 1024
#define OFF_YX1   1050624    // 1024
#define OFF_YX2   1051648    // 1024
#define OFF_PX    1052672    // 4096
#define OFF_EPART 1057792    // 1024 (accumulators, init'd by prep blk 392 each launch)

typedef __attribute__((ext_vector_type(8))) short bf16x8;
typedef __attribute__((ext_vector_type(4))) float f32x4;

__device__ __forceinline__ short f2bf(float f) {
    unsigned u = __float_as_uint(f);
    unsigned r = u + 0x7fffu + ((u >> 16) & 1u);
    return (short)(r >> 16);
}

// packed f32x2 -> bf16x2 (RTNE), 1 VALU op per 2 values (no builtin on gfx950)
__device__ __forceinline__ unsigned cvt_pk_bf16(float lo, float hi) {
    unsigned r;
    asm("v_cvt_pk_bf16_f32 %0, %1, %2" : "=v"(r) : "v"(lo), "v"(hi));
    return r;
}

__device__ __forceinline__ void pack8_store(const float4& A, const float4& B, short* dst) {
    uint4 v;
    v.x = cvt_pk_bf16(A.x, A.y);
    v.y = cvt_pk_bf16(A.z, A.w);
    v.z = cvt_pk_bf16(B.x, B.y);
    v.w = cvt_pk_bf16(B.z, B.w);
    *(uint4*)dst = v;
}

// Monotone float<->uint encoding: enc preserves order under UNSIGNED compare,
// so atomicMin/atomicMax on the encoding give deterministic float min/max.
__device__ __forceinline__ unsigned encf(float f) {
    unsigned u = __float_as_uint(f);
    return (u >> 31) ? ~u : (u | 0x80000000u);
}
__device__ __forceinline__ float decf(unsigned u) {
    return __uint_as_float((u >> 31) ? (u & 0x7fffffffu) : ~u);
}

// ===== PREP: qkv 8-row (384) + yproj (4) + xpool (4) + epool-init (1) = 393 blocks =====
__global__ __launch_bounds__(256) void prep_kernel(
    const float* __restrict__ x, const float* __restrict__ e, const float* __restrict__ y,
    const float* __restrict__ nm,
    const float* __restrict__ Wq, const float* __restrict__ Wk, const float* __restrict__ Wv,
    const float* __restrict__ Wye_add, const float* __restrict__ Wye_mul,
    const float* __restrict__ Wyx_add, const float* __restrict__ Wyx_mul,
    float* __restrict__ ws) {

    __shared__ float smem[16 * 256];
    const int blk = blockIdx.x;
    const int t = threadIdx.x;

    if (blk < 384) {
        const int which = blk >> 7;          // 128 row-blocks per W
        const int m0 = (blk & 127) * 8;      // 8 rows per block
        const float* W = which == 0 ? Wq : (which == 1 ? Wk : Wv);
        float* out = ws + (size_t)which * 262144;
        float (*xl)[256] = (float(*)[256])smem;
        for (int r = 0; r < 8; ++r) xl[r][t] = x[(m0 + r) * 256 + t];
        __syncthreads();
        float acc[8];
#pragma unroll
        for (int r = 0; r < 8; ++r) acc[r] = 0.f;
        for (int d = 0; d < 256; d += 4) {
            float w0 = W[(d + 0) * 256 + t];
            float w1 = W[(d + 1) * 256 + t];
            float w2 = W[(d + 2) * 256 + t];
            float w3 = W[(d + 3) * 256 + t];
#pragma unroll
            for (int r = 0; r < 8; ++r) {
                float4 ev = *(const float4*)&xl[r][d];
                acc[r] = fmaf(ev.x, w0, fmaf(ev.y, w1, fmaf(ev.z, w2, fmaf(ev.w, w3, acc[r]))));
            }
        }
        if (which == 0) {
            // Q stays row-major [b][i][c]
#pragma unroll
            for (int r = 0; r < 8; ++r) {
                int m = m0 + r;
                out[m * 256 + t] = acc[r] * nm[m];
            }
        } else {
            // K,V stored TRANSPOSED [b][c][j]; m0 = b*256 + jloc
            const int bb2  = m0 >> 8;
            const int jloc = m0 & 255;
            float tv[8];
#pragma unroll
            for (int r = 0; r < 8; ++r) tv[r] = acc[r] * nm[m0 + r];
            float* outb = out + (size_t)bb2 * 65536 + t * 256 + jloc;
            *(float4*)&outb[0] = make_float4(tv[0], tv[1], tv[2], tv[3]);
            *(float4*)&outb[4] = make_float4(tv[4], tv[5], tv[6], tv[7]);
        }
    } else if (blk < 388) {
        const int b = blk - 384;
        float a1 = 0.f, a2 = 0.f, a3 = 0.f, a4 = 0.f;
        for (int k = 0; k < DYY; ++k) {
            float yv = y[b * DYY + k];
            a1 = fmaf(yv, Wye_add[k * 256 + t], a1);
            a2 = fmaf(yv, Wye_mul[k * 256 + t], a2);
            a3 = fmaf(yv, Wyx_add[k * 256 + t], a3);
            a4 = fmaf(yv, Wyx_mul[k * 256 + t], a4);
        }
        ws[OFF_YE1 + b * 256 + t] = a1;
        ws[OFF_YE2 + b * 256 + t] = a2;
        ws[OFF_YX1 + b * 256 + t] = a3;
        ws[OFF_YX2 + b * 256 + t] = a4;
    } else if (blk < 392) {
        const int b = blk - 388;
        float s = 0.f, q = 0.f, mn = 1e30f, mx = -1e30f;
        for (int i = 0; i < 256; ++i) {
            float v = x[(b * 256 + i) * 256 + t];
            s += v; q = fmaf(v, v, q);
            mn = fminf(mn, v); mx = fmaxf(mx, v);
        }
        float mean = s * (1.f / 256.f);
        float var  = (q - s * s * (1.f / 256.f)) * (1.f / 255.f);
        var = fmaxf(var, 0.f);
        ws[OFF_PX + b * 1024 + t]       = mean;
        ws[OFF_PX + b * 1024 + 256 + t] = mn;
        ws[OFF_PX + b * 1024 + 512 + t] = mx;
        ws[OFF_PX + b * 1024 + 768 + t] = sqrtf(var);
    } else {
        // init e-pool accumulators (re-done EVERY launch -> graph replays are clean)
        float* ep = ws + OFF_EPART;
        ep[t]       = 0.f;                         // esum
        ep[256 + t] = 0.f;                         // esq
        ((unsigned*)ep)[512 + t] = 0u;             // enc(max) identity (smallest)
        ((unsigned*)ep)[768 + t] = 0xFFFFFFFFu;    // enc(min) identity (largest)
    }
}

// ============ FUSED: E1/E2 (MFMA) + Y + online softmax + newE (MFMA) + xw + e-pool ============
// ONE barrier per chunk (see R7). KEEP __launch_bounds__(256,2): R8 measured (256,3)
// forces VGPR 112->84, spilling weight frags (FETCH 43->190 MB, dur 95.6->177 us).
// e-pool stats accumulated on the float e values already loaded (math verified in R11's
// pre-timing check); block-reduced via LDS (ypl reused), then combined via GLOBAL ATOMICS
// into a 1024-float accumulator (R11's per-(b,i) partial store overflowed ws -> OOB).
#define EBP  72
#define YPLP 264

#define ESTAT(k, v) { es[k] += (v); eq[k] = fmaf((v), (v), eq[k]); \
                      emn[k] = fminf(emn[k], (v)); emx[k] = fmaxf(emx[k], (v)); }
#define ESTAT8(A, B) { ESTAT(0, A.x) ESTAT(1, A.y) ESTAT(2, A.z) ESTAT(3, A.w) \
                       ESTAT(4, B.x) ESTAT(5, B.y) ESTAT(6, B.z) ESTAT(7, B.w) }

__global__ __launch_bounds__(256, 2) void fusedmfma_kernel(
    const float* __restrict__ e, const float* __restrict__ nmask,
    const float* __restrict__ Wm, const float* __restrict__ Wa,
    const float* __restrict__ We_out, const float* __restrict__ be_out,
    const float* __restrict__ ws, float* __restrict__ outE, float* __restrict__ xw,
    float* __restrict__ epart) {

    const int i = blockIdx.x, b = blockIdx.y;
    const int tid  = threadIdx.x;
    const int w    = tid >> 6;
    const int lane = tid & 63;
    const int quad = lane >> 4, l16 = lane & 15;

    __shared__ __align__(16) short ebuf[2][32 * EBP];   //  9216 B
    __shared__ __align__(16) short ypl[2][32 * YPLP];   // 33792 B (reused as e-pool scratch)
    __shared__ float nml[256];                          //  1024 B -> 44032 B total

    nml[tid] = nmask[b * 256 + tid];

    bf16x8 bm[4][2], ba[4][2], bw[8];
    const int cw = w * 64;
#pragma unroll
    for (int ct = 0; ct < 4; ++ct) {
        const int c = cw + ct * 16 + l16;
#pragma unroll
        for (int s = 0; s < 2; ++s) {
            bf16x8 t1, t2;
#pragma unroll
            for (int jj = 0; jj < 8; ++jj) {
                const int d = s * 32 + quad * 8 + jj;
                t1[jj] = f2bf(Wm[d * 256 + c]);
                t2[jj] = f2bf(Wa[d * 256 + c]);
            }
            bm[ct][s] = t1; ba[ct][s] = t2;
        }
    }
    const int cp = w * 16 + l16;
    {
#pragma unroll
        for (int s = 0; s < 8; ++s) {
            bf16x8 t;
#pragma unroll
            for (int jj = 0; jj < 8; ++jj) {
                const int cch = s * 32 + quad * 8 + jj;
                t[jj] = f2bf(We_out[cch * 64 + cp]);
            }
            bw[s] = t;
        }
    }
    const float bo = be_out[cp];

    const float rs = 0.17677669529663687f;
    float qc[4], ye1c[4], ye2c[4];
#pragma unroll
    for (int ct = 0; ct < 4; ++ct) {
        const int c = cw + ct * 16 + l16;
        qc[ct]   = ws[OFF_Q + (size_t)(b * 256 + i) * 256 + c] * rs;
        ye1c[ct] = ws[OFF_YE1 + b * 256 + c];
        ye2c[ct] = ws[OFF_YE2 + b * 256 + c] + 1.f;
    }
    const float* kTb = ws + OFF_K + (size_t)b * 65536;   // [c][j]
    const float* vTb = ws + OFF_V + (size_t)b * 65536;   // [c][j]

    // e-pool per-thread stats over this thread's 8 columns (c0..c0+7), 8 rows
    float es[8], eq[8], emn[8], emx[8];
#pragma unroll
    for (int k = 0; k < 8; ++k) { es[k] = 0.f; eq[k] = 0.f; emn[k] = 1e30f; emx[k] = -1e30f; }

    const float* eb = e + ((size_t)(b * 256 + i)) * 256 * 64;
    const int jr = tid >> 3, c0 = (tid & 7) * 8;
    {
        float4 A = *(const float4*)(eb + jr * 64 + c0);
        float4 B = *(const float4*)(eb + jr * 64 + c0 + 4);
        ESTAT8(A, B)
        pack8_store(A, B, &ebuf[0][jr * EBP + c0]);
    }
    __syncthreads();
    const float mi = nml[i];
    const size_t outbase = (size_t)(b * 256 + i) * 256;

    float msm[4], lsm[4], wsm[4];
#pragma unroll
    for (int ct = 0; ct < 4; ++ct) { msm[ct] = -1e30f; lsm[ct] = 0.f; wsm[ct] = 0.f; }

    for (int chunk = 0; chunk < 8; ++chunk) {
        const int cur = chunk & 1, j0 = chunk * 32;

        // e prefetch (HBM/L3) issued first — consumed at end of S1
        float4 pfA, pfB;
        if (chunk < 7) {
            const float* nb = eb + (size_t)(j0 + 32 + jr) * 64 + c0;
            pfA = *(const float4*)(nb);
            pfB = *(const float4*)(nb + 4);
        }

        bf16x8 ae[2][2];
#pragma unroll
        for (int jt = 0; jt < 2; ++jt)
#pragma unroll
            for (int s = 0; s < 2; ++s)
                ae[jt][s] = *(const bf16x8*)&ebuf[cur][(jt * 16 + l16) * EBP + s * 32 + quad * 8];

        float emv[8];
#pragma unroll
        for (int jt = 0; jt < 2; ++jt)
#pragma unroll
            for (int r = 0; r < 4; ++r)
                emv[jt * 4 + r] = mi * nml[j0 + jt * 16 + quad * 4 + r];

#pragma unroll
        for (int ct = 0; ct < 4; ++ct) {
            const int c = cw + ct * 16 + l16;

            // K/V from transposed layout: 4 float4 loads (vs 32 scalar loads)
            const float4 K0 = *(const float4*)&kTb[c * 256 + j0 + quad * 4];
            const float4 K1 = *(const float4*)&kTb[c * 256 + j0 + 16 + quad * 4];
            const float4 V0 = *(const float4*)&vTb[c * 256 + j0 + quad * 4];
            const float4 V1 = *(const float4*)&vTb[c * 256 + j0 + 16 + quad * 4];
            const float Ks[8] = {K0.x, K0.y, K0.z, K0.w, K1.x, K1.y, K1.z, K1.w};
            const float Vs[8] = {V0.x, V0.y, V0.z, V0.w, V1.x, V1.y, V1.z, V1.w};

            f32x4 a1_0 = {0.f, 0.f, 0.f, 0.f}, a1_1 = {0.f, 0.f, 0.f, 0.f};
            f32x4 a2_0 = {0.f, 0.f, 0.f, 0.f}, a2_1 = {0.f, 0.f, 0.f, 0.f};
#pragma unroll
            for (int s = 0; s < 2; ++s) {
                a1_0 = __builtin_amdgcn_mfma_f32_16x16x32_bf16(ae[0][s], bm[ct][s], a1_0, 0, 0, 0);
                a1_1 = __builtin_amdgcn_mfma_f32_16x16x32_bf16(ae[1][s], bm[ct][s], a1_1, 0, 0, 0);
                a2_0 = __builtin_amdgcn_mfma_f32_16x16x32_bf16(ae[0][s], ba[ct][s], a2_0, 0, 0, 0);
                a2_1 = __builtin_amdgcn_mfma_f32_16x16x32_bf16(ae[1][s], ba[ct][s], a2_1, 0, 0, 0);
            }

            float Ys[8];
#pragma unroll
            for (int jt = 0; jt < 2; ++jt) {
                float yv[4];
#pragma unroll
                for (int r = 0; r < 4; ++r) {
                    const int u  = jt * 4 + r;
                    const float e1v = (jt == 0) ? a1_0[r] : a1_1[r];
                    const float e2v = (jt == 0) ? a2_0[r] : a2_1[r];
                    const float em = emv[u];
                    const float Yv = fmaf(qc[ct] * Ks[u], fmaf(e1v, em, 1.f), e2v * em);
                    yv[r] = fmaf(ye2c[ct], Yv, ye1c[ct]);
                    Ys[u] = (em > 0.f) ? Yv : -1e9f;
                }
                const int jl0 = jt * 16 + quad * 4;
                unsigned short* yb = (unsigned short*)&ypl[cur][jl0 * YPLP + c];
                const unsigned p01 = cvt_pk_bf16(yv[0], yv[1]);
                const unsigned p23 = cvt_pk_bf16(yv[2], yv[3]);
                yb[0]        = (unsigned short)p01;
                yb[YPLP]     = (unsigned short)(p01 >> 16);
                yb[2 * YPLP] = (unsigned short)p23;
                yb[3 * YPLP] = (unsigned short)(p23 >> 16);
            }
            float cm = Ys[0];
#pragma unroll
            for (int u = 1; u < 8; ++u) cm = fmaxf(cm, Ys[u]);
            const float mnew = fmaxf(msm[ct], cm);
            const float al = __expf(msm[ct] - mnew);
            float sum = 0.f, wsum = 0.f;
#pragma unroll
            for (int u = 0; u < 8; ++u) {
                const float p = __expf(Ys[u] - mnew);
                sum += p; wsum = fmaf(p, Vs[u], wsum);
            }
            lsm[ct] = fmaf(lsm[ct], al, sum);
            wsm[ct] = fmaf(wsm[ct], al, wsum);
            msm[ct] = mnew;
        }

        if (chunk < 7) {
            ESTAT8(pfA, pfB)
            pack8_store(pfA, pfB, &ebuf[cur ^ 1][jr * EBP + c0]);
        }
        __syncthreads();   // the ONLY barrier per chunk

        f32x4 acc0 = {0.f, 0.f, 0.f, 0.f}, acc1 = {0.f, 0.f, 0.f, 0.f};
#pragma unroll
        for (int s = 0; s < 8; ++s) {
            bf16x8 a0 = *(const bf16x8*)&ypl[cur][(l16) * YPLP + s * 32 + quad * 8];
            bf16x8 a1 = *(const bf16x8*)&ypl[cur][(16 + l16) * YPLP + s * 32 + quad * 8];
            acc0 = __builtin_amdgcn_mfma_f32_16x16x32_bf16(a0, bw[s], acc0, 0, 0, 0);
            acc1 = __builtin_amdgcn_mfma_f32_16x16x32_bf16(a1, bw[s], acc1, 0, 0, 0);
        }
#pragma unroll
        for (int jt = 0; jt < 2; ++jt)
#pragma unroll
            for (int r = 0; r < 4; ++r) {
                const int jl = jt * 16 + quad * 4 + r;
                const int jg = j0 + jl;
                const float em2 = mi * nml[jg];
                const float av = (jt == 0) ? acc0[r] : acc1[r];
                outE[(outbase + jg) * 64 + cp] = (av + bo) * em2;
            }
    }

    // ---- e-pool block reduction -> 64 per-column stats -> global atomics ----
    __syncthreads();               // all ypl[cur] reads of chunk 7 done before overwrite
    {
        float* sred = (float*)ypl; // stride 260 spreads jr across banks
        const int cg = tid & 7;
        const int jr2 = tid >> 3;
#pragma unroll
        for (int k = 0; k < 8; ++k)
            *(float4*)&sred[jr2 * 260 + (cg * 8 + k) * 4] =
                make_float4(es[k], eq[k], emn[k], emx[k]);
        __syncthreads();
        if (tid < 64) {
            float4 a = make_float4(0.f, 0.f, 1e30f, -1e30f);
            for (int j = 0; j < 32; ++j) {
                float4 v = *(const float4*)&sred[j * 260 + tid * 4];
                a.x += v.x; a.y += v.y;
                a.z = fminf(a.z, v.z); a.w = fmaxf(a.w, v.w);
            }
            atomicAdd(&epart[b * 64 + tid], a.x);              // sum
            atomicAdd(&epart[256 + b * 64 + tid], a.y);        // sumsq
            atomicMax((unsigned*)epart + 512 + b * 64 + tid, encf(a.w));  // max
            atomicMin((unsigned*)epart + 768 + b * 64 + tid, encf(a.z));  // min
        }
    }

#pragma unroll
    for (int ct = 0; ct < 4; ++ct) {
        float m = msm[ct], l = lsm[ct], wv = wsm[ct];
#pragma unroll
        for (int off = 16; off < 64; off <<= 1) {
            const float m2 = __shfl_xor(m, off, 64);
            const float l2 = __shfl_xor(l, off, 64);
            const float w2 = __shfl_xor(wv, off, 64);
            const float mn = fmaxf(m, m2);
            const float s1 = __expf(m - mn), s2 = __expf(m2 - mn);
            l = l * s1 + l2 * s2;
            wv = wv * s1 + w2 * s2;
            m = mn;
        }
        if (quad == 0) {
            const int c = cw + ct * 16 + l16;
            const float weighted = wv / l;
            const float yx1 = ws[OFF_YX1 + b * 256 + c];
            const float yx2 = ws[OFF_YX2 + b * 256 + c] + 1.f;
            xw[(size_t)(b * 256 + i) * 256 + c] = fmaf(yx2, weighted, yx1);
        }
    }
}

// ========== POST: rowgemm 8-row blocks (128) + per-batch newY (4 blocks) = 132 blocks ==========
__global__ __launch_bounds__(256) void post_kernel(
    const float* __restrict__ xwin, const float* __restrict__ Wx_out,
    const float* __restrict__ bx_out, const float* __restrict__ nm,
    const float* __restrict__ y,
    const float* __restrict__ Wyy, const float* __restrict__ Wxy,
    const float* __restrict__ bxy, const float* __restrict__ Wey,
    const float* __restrict__ bey, const float* __restrict__ Wy_out,
    const float* __restrict__ by_out,
    const float* __restrict__ ws, float* __restrict__ outX, float* __restrict__ outY) {

    __shared__ float smem[16 * 256];
    const int blk = blockIdx.x;
    const int t = threadIdx.x;

    if (blk < 128) {
        const int m0 = blk * 8;
        float (*xl)[256] = (float(*)[256])smem;
        for (int r = 0; r < 8; ++r) xl[r][t] = xwin[(m0 + r) * 256 + t];
        __syncthreads();
        float acc[8];
#pragma unroll
        for (int r = 0; r < 8; ++r) acc[r] = 0.f;
        for (int d = 0; d < 256; d += 4) {
            float w0 = Wx_out[(d + 0) * 256 + t];
            float w1 = Wx_out[(d + 1) * 256 + t];
            float w2 = Wx_out[(d + 2) * 256 + t];
            float w3 = Wx_out[(d + 3) * 256 + t];
#pragma unroll
            for (int r = 0; r < 8; ++r) {
                float4 ev = *(const float4*)&xl[r][d];
                acc[r] = fmaf(ev.x, w0, fmaf(ev.y, w1, fmaf(ev.z, w2, fmaf(ev.w, w3, acc[r]))));
            }
        }
        const float bv = bx_out[t];
#pragma unroll
        for (int r = 0; r < 8; ++r) {
            int m = m0 + r;
            outX[m * 256 + t] = (acc[r] + bv) * nm[m];
        }
    } else {
        // one block per batch; e-pool stats read directly from global accumulators
        const int b = blk - 128;
        float* pe = smem;             // 256 floats: mean|min|max|std
        if (t < 64) {
            const float* ep = ws + OFF_EPART;
            const float S = ep[b * 64 + t];
            const float Q = ep[256 + b * 64 + t];
            const unsigned mxe = ((const unsigned*)ep)[512 + b * 64 + t];
            const unsigned mne = ((const unsigned*)ep)[768 + b * 64 + t];
            const float n = 65536.f;
            float meane = S / n;
            float vare  = fmaxf((Q - S * S / n) / (n - 1.f), 0.f);
            pe[t]       = meane;
            pe[64 + t]  = decf(mne);
            pe[128 + t] = decf(mxe);
            pe[192 + t] = sqrtf(vare);
        }
        __syncthreads();
        const int o = t & 63, ks = t >> 6;
        float a = 0.f;
        if (ks == 0) {
            a = bxy[o] + bey[o];
            for (int k = 0; k < 64; ++k) a = fmaf(y[b * 64 + k], Wyy[k * 64 + o], a);
        }
        for (int k = ks * 64; k < ks * 64 + 64; ++k) a = fmaf(pe[k], Wey[k * 64 + o], a);
        const float* px = ws + OFF_PX + b * 1024;
        for (int k = ks * 256; k < ks * 256 + 256; ++k) a = fmaf(px[k], Wxy[k * 64 + o], a);
        float* redB = smem + 256;
        redB[ks * 64 + o] = a;
        __syncthreads();
        float* sy = smem + 512;
        if (ks == 0) sy[o] = redB[o] + redB[64 + o] + redB[128 + o] + redB[192 + o];
        __syncthreads();
        if (t < 64) {
            float r = by_out[t];
            for (int k = 0; k < 64; ++k) r = fmaf(sy[k], Wy_out[k * 64 + t], r);
            outY[b * 64 + t] = r;
        }
    }
}

extern "C" void kernel_launch(void* const* d_in, const int* in_sizes, int n_in,
                              void* d_out, int out_size, void* d_ws, size_t ws_size,
                              hipStream_t stream) {
    const float* x        = (const float*)d_in[0];
    const float* e        = (const float*)d_in[1];
    const float* y        = (const float*)d_in[2];
    const float* nm       = (const float*)d_in[3];
    const float* Wq       = (const float*)d_in[4];
    const float* Wk       = (const float*)d_in[5];
    const float* Wv       = (const float*)d_in[6];
    const float* We_mul   = (const float*)d_in[7];
    const float* We_add   = (const float*)d_in[8];
    const float* Wye_add  = (const float*)d_in[9];
    const float* Wye_mul  = (const float*)d_in[10];
    const float* Wyx_add  = (const float*)d_in[11];
    const float* Wyx_mul  = (const float*)d_in[12];
    const float* Wyy      = (const float*)d_in[13];
    const float* Wxy      = (const float*)d_in[14];
    const float* bxy      = (const float*)d_in[15];
    const float* Wey      = (const float*)d_in[16];
    const float* bey      = (const float*)d_in[17];
    const float* We_out   = (const float*)d_in[18];
    const float* be_out   = (const float*)d_in[19];
    const float* Wx_out   = (const float*)d_in[20];
    const float* bx_out   = (const float*)d_in[21];
    const float* Wy_out   = (const float*)d_in[22];
    const float* by_out   = (const float*)d_in[23];

    float* ws   = (float*)d_ws;
    float* outX = (float*)d_out;
    float* outE = (float*)d_out + 262144;
    float* outY = (float*)d_out + 262144 + 16777216;

    // 384 qkv + 4 yproj + 4 xpool + 1 epool-init = 393 blocks
    prep_kernel<<<393, 256, 0, stream>>>(x, e, y, nm, Wq, Wk, Wv,
                                         Wye_add, Wye_mul, Wyx_add, Wyx_mul, ws);
    fusedmfma_kernel<<<dim3(256, 4), 256, 0, stream>>>(e, nm, We_mul, We_add, We_out, be_out,
                                                       ws, outE, ws + OFF_XW,
                                                       ws + OFF_EPART);
    // 128 rowgemm blocks + 4 per-batch newY blocks (blk 128..131) => 132 blocks
    post_kernel<<<132, 256, 0, stream>>>(ws + OFF_XW, Wx_out, bx_out, nm, y,
                                         Wyy, Wxy, bxy, Wey, bey, Wy_out, by_out,
                                         ws, outX, outY);
}